// Round 7
// baseline (213.117 us; speedup 1.0000x reference)
//
#include <hip/hip_runtime.h>
#include <hip/hip_bf16.h>
#include <cstdint>

#define TDIM 517
#define FEATD 120
#define NBB 16
#define NHEAD 24
#define NDIM 128
#define NKC 3072            // NHEAD*NDIM
#define MROWS (NBB * TDIM)  // 8272
#define MPAD 8320           // 65 * 128
#define NCOLS (3 * NKC)     // 9216
#define KPAD 128
#define LN_EPS 1e-5f

typedef short bf16x8 __attribute__((ext_vector_type(8)));
typedef short bf16x4 __attribute__((ext_vector_type(4)));
typedef float f32x4 __attribute__((ext_vector_type(4)));

static __device__ __forceinline__ float bf2f(ushort u) {
  union { uint i; float f; } v; v.i = ((uint)u) << 16; return v.f;
}
static __device__ __forceinline__ ushort f2bf(float f) {
  __hip_bfloat16 h = __float2bfloat16(f);   // RNE
  return *reinterpret_cast<ushort*>(&h);
}

// ---------------------------------------------------------------------------
// K0a: x [16][120][517] f32  ->  A [row=(bb*517+tt)][kpad=128] bf16 (f>=120 zero)
// ---------------------------------------------------------------------------
__global__ __launch_bounds__(256) void convert_x_kernel(
    const float* __restrict__ x, ushort* __restrict__ A)
{
  __shared__ float tile[FEATD][65];
  const int tid = threadIdx.x;
  const int bb = blockIdx.y;
  const int t0 = blockIdx.x * 64;
  const int nt = min(64, TDIM - t0);
  for (int idx = tid; idx < FEATD * 64; idx += 256) {
    int f = idx >> 6, tl = idx & 63;
    if (tl < nt) tile[f][tl] = x[((size_t)bb * FEATD + f) * TDIM + t0 + tl];
  }
  __syncthreads();
  for (int c = tid; c < 64 * 16; c += 256) {
    int tl = c >> 4, c8 = c & 15;
    if (tl >= nt) continue;
    ushort u[8];
    if (c8 < 15) {
#pragma unroll
      for (int j = 0; j < 8; ++j) u[j] = f2bf(tile[c8 * 8 + j][tl]);
    } else {
#pragma unroll
      for (int j = 0; j < 8; ++j) u[j] = 0;
    }
    size_t row = (size_t)bb * TDIM + t0 + tl;
    *reinterpret_cast<uint4*>(A + row * KPAD + c8 * 8) = *reinterpret_cast<const uint4*>(u);
  }
}

// ---------------------------------------------------------------------------
// K0b: W{q,k,v} [3072][120] f32 -> B [9216][128] bf16; also zero A tail rows
// ---------------------------------------------------------------------------
__global__ __launch_bounds__(256) void convert_w_kernel(
    const float* __restrict__ Wq, const float* __restrict__ Wk, const float* __restrict__ Wv,
    ushort* __restrict__ B, ushort* __restrict__ A)
{
  const int c = blockIdx.x * 256 + threadIdx.x;
  if (c < NCOLS * 16) {
    int col = c >> 4, c8 = c & 15;
    ushort u[8];
    if (c8 < 15) {
      const float* W = (col < NKC)     ? (Wq + (size_t)col * FEATD)
                     : (col < 2 * NKC) ? (Wk + (size_t)(col - NKC) * FEATD)
                                       : (Wv + (size_t)(col - 2 * NKC) * FEATD);
#pragma unroll
      for (int j = 0; j < 8; ++j) u[j] = f2bf(W[c8 * 8 + j]);
    } else {
#pragma unroll
      for (int j = 0; j < 8; ++j) u[j] = 0;
    }
    *reinterpret_cast<uint4*>(B + (size_t)col * KPAD + c8 * 8) = *reinterpret_cast<const uint4*>(u);
  }
  if (c < (MPAD - MROWS) * 16) {
    uint4 z = {0, 0, 0, 0};
    *reinterpret_cast<uint4*>(A + (size_t)(MROWS + (c >> 4)) * KPAD + (c & 15) * 8) = z;
  }
}

// ---------------------------------------------------------------------------
// K1: MFMA projection GEMM (unchanged from R2)
// ---------------------------------------------------------------------------
__global__ __launch_bounds__(256) void proj_mfma_kernel(
    const ushort* __restrict__ A, const ushort* __restrict__ B,
    const float* __restrict__ bq, const float* __restrict__ bk, const float* __restrict__ bv,
    ushort* __restrict__ qb, ushort* __restrict__ kb, ushort* __restrict__ vb)
{
  __shared__ __align__(16) ushort sA[128 * KPAD];
  __shared__ __align__(16) ushort sB[128 * KPAD];
  __shared__ float sBias[128];
  const int tid  = threadIdx.x;
  const int lane = tid & 63;
  const int wave = tid >> 6;
  const int wm0  = (wave >> 1) * 64;
  const int wn0  = (wave & 1) * 64;
  const int m0   = blockIdx.x * 128;
  const int n0   = blockIdx.y * 128;
  const int mat  = blockIdx.y / 24;
  const int nloc0 = n0 - mat * NKC;
  const float* bias = (mat == 0) ? bq : (mat == 1) ? bk : bv;
  ushort* outb      = (mat == 0) ? qb : (mat == 1) ? kb : vb;

  if (tid < 128) sBias[tid] = bias[nloc0 + tid];

#pragma unroll
  for (int i = 0; i < 8; ++i) {
    int c = tid + i * 256;
    int row = c >> 4, c8 = c & 15;
    uint4 va = *reinterpret_cast<const uint4*>(A + (size_t)(m0 + row) * KPAD + c8 * 8);
    uint4 vb4 = *reinterpret_cast<const uint4*>(B + (size_t)(n0 + row) * KPAD + c8 * 8);
    *reinterpret_cast<uint4*>(&sA[row * KPAD + ((c8 ^ (row & 7)) << 3)]) = va;
    *reinterpret_cast<uint4*>(&sB[row * KPAD + ((c8 ^ (row & 7)) << 3)]) = vb4;
  }
  __syncthreads();

  f32x4 acc[4][4];
#pragma unroll
  for (int i = 0; i < 4; ++i)
#pragma unroll
    for (int j = 0; j < 4; ++j) acc[i][j] = (f32x4){0.f, 0.f, 0.f, 0.f};

  const int rl = lane & 15;
  const int kg = lane >> 4;
#pragma unroll
  for (int s = 0; s < 4; ++s) {
    bf16x8 af[4], bfr[4];
    const int c8 = s * 4 + kg;
#pragma unroll
    for (int i = 0; i < 4; ++i) {
      int row = wm0 + i * 16 + rl;
      af[i] = *reinterpret_cast<const bf16x8*>(&sA[row * KPAD + ((c8 ^ (row & 7)) << 3)]);
      int rowb = wn0 + i * 16 + rl;
      bfr[i] = *reinterpret_cast<const bf16x8*>(&sB[rowb * KPAD + ((c8 ^ (rowb & 7)) << 3)]);
    }
#pragma unroll
    for (int i = 0; i < 4; ++i)
#pragma unroll
      for (int j = 0; j < 4; ++j)
        acc[i][j] = __builtin_amdgcn_mfma_f32_16x16x32_bf16(af[i], bfr[j], acc[i][j], 0, 0, 0);
  }

  __syncthreads();
  ushort* sC = sA;
#pragma unroll
  for (int i = 0; i < 4; ++i)
#pragma unroll
    for (int j = 0; j < 4; ++j) {
      int col = wn0 + j * 16 + rl;
      float bsv = sBias[col];
#pragma unroll
      for (int r = 0; r < 4; ++r) {
        int row = wm0 + i * 16 + kg * 4 + r;
        sC[row * 128 + col] = f2bf(acc[i][j][r] + bsv);
      }
    }
  __syncthreads();
#pragma unroll
  for (int i = 0; i < 8; ++i) {
    int c = tid + i * 256;
    int row = c >> 4, c8 = c & 15;
    int grow = m0 + row;
    if (grow < MROWS)
      *reinterpret_cast<uint4*>(outb + (size_t)grow * NKC + nloc0 + c8 * 8) =
          *reinterpret_cast<const uint4*>(&sC[row * 128 + c8 * 8]);
  }
}

// ---------------------------------------------------------------------------
// K2: MFMA attention + fused LN partial stats (unchanged from R6)
// ---------------------------------------------------------------------------
#define WAVE_LDS 5760
__global__ __launch_bounds__(256) void attn_mfma_kernel(
    const ushort* __restrict__ qb, const ushort* __restrict__ kb,
    const ushort* __restrict__ vb, float* __restrict__ obuf,
    float* __restrict__ part)
{
  __shared__ __align__(16) ushort lds[4 * WAVE_LDS];
  const int tid  = threadIdx.x;
  const int wave = tid >> 6;
  const int lane = tid & 63;
  const int c = lane & 15;
  const int g = lane >> 4;
  const int p = blockIdx.x * 4 + wave;
  ushort* vT = lds + wave * WAVE_LDS;   // [n][36]: vT[n*36+m] = V[m][n]
  ushort* wL = vT + 4608;               // [row][36]: wei
  const ushort* qp = qb + (size_t)p * NKC;
  const ushort* kp = kb + (size_t)p * NKC;
  const ushort* vp = vb + (size_t)p * NKC;

  // ---- issue V global loads early (T14: hide under QK^T+softmax) ----
  uint4 vload[6];
#pragma unroll
  for (int it = 0; it < 6; ++it) {
    int idx = it * 64 + lane;
    int m = idx >> 4, n0 = (idx & 15) * 8;
    vload[it] = *reinterpret_cast<const uint4*>(vp + m * 128 + n0);
  }

  // ---- QK^T: S[kk][m], kk rows on A(Q), m cols on B(K) ----
  f32x4 sc[2][2];
#pragma unroll
  for (int i = 0; i < 2; ++i)
#pragma unroll
    for (int j = 0; j < 2; ++j) sc[i][j] = (f32x4){0.f, 0.f, 0.f, 0.f};

#pragma unroll
  for (int s = 0; s < 4; ++s) {
    bf16x8 aq[2], bk2[2];
#pragma unroll
    for (int i = 0; i < 2; ++i)
      aq[i] = *reinterpret_cast<const bf16x8*>(qp + (i * 16 + c) * 128 + s * 32 + g * 8);
#pragma unroll
    for (int j = 0; j < 2; ++j)
      bk2[j] = *reinterpret_cast<const bf16x8*>(kp + (j * 16 + c) * 128 + s * 32 + g * 8);
#pragma unroll
    for (int i = 0; i < 2; ++i)
#pragma unroll
      for (int j = 0; j < 2; ++j)
        sc[i][j] = __builtin_amdgcn_mfma_f32_16x16x32_bf16(aq[i], bk2[j], sc[i][j], 0, 0, 0);
  }

  // ---- softmax over m per row; lane holds S[i*16+g*4+r][j*16+c] ----
#pragma unroll
  for (int i = 0; i < 2; ++i) {
#pragma unroll
    for (int r = 0; r < 4; ++r) {
      float s0 = sc[i][0][r];
      float s1 = (c < 8) ? sc[i][1][r] : -1e30f;
      float mx = fmaxf(s0, s1);
#pragma unroll
      for (int d = 1; d < 16; d <<= 1) mx = fmaxf(mx, __shfl_xor(mx, d));
      float e0 = __expf(s0 - mx);
      float e1 = (c < 8) ? __expf(s1 - mx) : 0.f;
      float sum = e0 + e1;
#pragma unroll
      for (int d = 1; d < 16; d <<= 1) sum += __shfl_xor(sum, d);
      float inv = 1.f / sum;
      int row = i * 16 + g * 4 + r;
      wL[row * 36 + c]      = f2bf(e0 * inv);
      wL[row * 36 + 16 + c] = f2bf(e1 * inv);
    }
  }

  // ---- stage V transposed: vT[n*36 + m] = V[m][n] (scalar scatter) ----
#pragma unroll
  for (int it = 0; it < 6; ++it) {
    int idx = it * 64 + lane;
    int m = idx >> 4, n0 = (idx & 15) * 8;
    uint w0 = vload[it].x, w1 = vload[it].y, w2 = vload[it].z, w3 = vload[it].w;
    vT[(n0 + 0) * 36 + m] = (ushort)(w0 & 0xffff);
    vT[(n0 + 1) * 36 + m] = (ushort)(w0 >> 16);
    vT[(n0 + 2) * 36 + m] = (ushort)(w1 & 0xffff);
    vT[(n0 + 3) * 36 + m] = (ushort)(w1 >> 16);
    vT[(n0 + 4) * 36 + m] = (ushort)(w2 & 0xffff);
    vT[(n0 + 5) * 36 + m] = (ushort)(w2 >> 16);
    vT[(n0 + 6) * 36 + m] = (ushort)(w3 & 0xffff);
    vT[(n0 + 7) * 36 + m] = (ushort)(w3 >> 16);
  }
  // zero pad m=24..31 for all n (ALL halfwords — R3 lesson)
#pragma unroll
  for (int h = 0; h < 16; ++h) {
    int idx = h * 64 + lane;        // 0..1023
    int n = idx >> 3, mm = 24 + (idx & 7);
    vT[n * 36 + mm] = 0;
  }

  // ---- PV A-frags (wei): row=i*16+c, k-chunk g*8 ----
  union FU { bf16x4 h[2]; bf16x8 v; };
  bf16x8 wa[2];
#pragma unroll
  for (int i = 0; i < 2; ++i) {
    FU u;
    u.h[0] = *reinterpret_cast<const bf16x4*>(wL + (i * 16 + c) * 36 + g * 8);
    u.h[1] = *reinterpret_cast<const bf16x4*>(wL + (i * 16 + c) * 36 + g * 8 + 4);
    wa[i] = u.v;
  }

  // ---- PV + O-write + LN partial accumulation ----
  float ls0[4] = {0.f, 0.f, 0.f, 0.f}, ls20[4] = {0.f, 0.f, 0.f, 0.f};
  float ls1[4] = {0.f, 0.f, 0.f, 0.f}, ls21[4] = {0.f, 0.f, 0.f, 0.f};
  float* op = obuf + (size_t)p * NKC;
#pragma unroll
  for (int nb = 0; nb < 8; ++nb) {
    FU u;
    const ushort* vrow = vT + (nb * 16 + c) * 36 + g * 8;
    u.h[0] = *reinterpret_cast<const bf16x4*>(vrow);
    u.h[1] = *reinterpret_cast<const bf16x4*>(vrow + 4);
    bf16x8 vf = u.v;
#pragma unroll
    for (int i = 0; i < 2; ++i) {
      f32x4 pv = (f32x4){0.f, 0.f, 0.f, 0.f};
      pv = __builtin_amdgcn_mfma_f32_16x16x32_bf16(wa[i], vf, pv, 0, 0, 0);
      if (i == 0) {
#pragma unroll
        for (int q = 0; q < 4; ++q) {
          op[(g * 4 + q) * 128 + nb * 16 + c] = pv[q];
          ls0[q] += pv[q];
          ls20[q] += pv[q] * pv[q];
        }
      } else if (g < 2) {
#pragma unroll
        for (int q = 0; q < 4; ++q) {
          op[(16 + g * 4 + q) * 128 + nb * 16 + c] = pv[q];
          ls1[q] += pv[q];
          ls21[q] += pv[q] * pv[q];
        }
      }
    }
  }

  // reduce over the 16-lane c-group (xor masks < 16 stay within group)
#pragma unroll
  for (int q = 0; q < 4; ++q) {
#pragma unroll
    for (int d = 1; d < 16; d <<= 1) {
      ls0[q]  += __shfl_xor(ls0[q], d);
      ls20[q] += __shfl_xor(ls20[q], d);
      ls1[q]  += __shfl_xor(ls1[q], d);
      ls21[q] += __shfl_xor(ls21[q], d);
    }
  }
  if (c == 0) {
    float* pr = part + (size_t)p * 48;
#pragma unroll
    for (int q = 0; q < 4; ++q) {
      int kk = g * 4 + q;
      pr[2 * kk]     = ls0[q];
      pr[2 * kk + 1] = ls20[q];
    }
    if (g < 2) {
#pragma unroll
      for (int q = 0; q < 4; ++q) {
        int kk = 16 + g * 4 + q;
        pr[2 * kk]     = ls1[q];
        pr[2 * kk + 1] = ls21[q];
      }
    }
  }
}

// ---------------------------------------------------------------------------
// K3: reduce per-(bb,t) partials -> stats (mu, rstd) per (bb,kk). ~1.6 MB read.
// ---------------------------------------------------------------------------
__global__ __launch_bounds__(256) void ln_part_reduce_kernel(
    const float* __restrict__ part, float* __restrict__ stats)
{
  const int b = blockIdx.x;  // bb*24+kk
  const int bb = b / NHEAD, kk = b % NHEAD;
  const int tid = threadIdx.x;
  float s = 0.f, s2 = 0.f;
  for (int tt = tid; tt < TDIM; tt += 256) {
    const float* pr = part + ((size_t)(bb * TDIM + tt)) * 48 + 2 * kk;
    s += pr[0];
    s2 += pr[1];
  }
  __shared__ float rs[256], rs2[256];
  rs[tid] = s; rs2[tid] = s2;
  __syncthreads();
  for (int off = 128; off > 0; off >>= 1) {
    if (tid < off) { rs[tid] += rs[tid + off]; rs2[tid] += rs2[tid + off]; }
    __syncthreads();
  }
  if (tid == 0) {
    const float inv = 1.f / (NDIM * TDIM);
    float mu = rs[0] * inv;
    float var = rs2[0] * inv - mu * mu;
    stats[b] = mu;
    stats[384 + b] = rsqrtf(var + LN_EPS);
  }
}

// ---------------------------------------------------------------------------
// K4: fused transpose + LN apply, pipelined multi-tile blocks.
// Block = (bb, kk, chunk of 4 t-tiles of 32). Reg-prefetch tile i+1 while
// computing/storing tile i (T14). LDS pad-129 -> read bank = (t+n)%32, 2-way.
// Stores: thread (n, t4) writes 4 consecutive t scalar; wave = 8 rows x 128B.
// ---------------------------------------------------------------------------
__global__ __launch_bounds__(256) void transpose_apply_kernel(
    const float* __restrict__ obuf, const float* __restrict__ stats,
    const float* __restrict__ gamma, const float* __restrict__ beta,
    float* __restrict__ out)
{
  __shared__ float tile[32][NDIM + 1];
  const int tid = threadIdx.x;
  const int bb = blockIdx.z, kk = blockIdx.y;
  const int chunk = blockIdx.x;             // 0..4
  const int tfirst = chunk * 4;             // tile index
  const int ntiles = (chunk == 4) ? 1 : 4;  // tiles 16 is the ragged tail
  const float mu = stats[bb * NHEAD + kk];
  const float rstd = stats[384 + bb * NHEAD + kk];

  const int ltl = tid >> 3;          // load row 0..31
  const int ln0 = (tid & 7) * 16;    // load col base (4 float4 per row-thread? no:)
  // load mapping: idx = tid + i*256 over 1024 float4s: tl = idx>>5, n4 = idx&31

  float4 pre[4];
  int t0 = tfirst * 32;

  // prime: load tile 0 of this chunk into regs
  {
    int nt = min(32, TDIM - t0);
#pragma unroll
    for (int i = 0; i < 4; ++i) {
      int idx = tid + i * 256;
      int tl = idx >> 5, n4 = idx & 31;
      if (tl < nt)
        pre[i] = *reinterpret_cast<const float4*>(
            obuf + ((size_t)(bb * TDIM + t0 + tl)) * NKC + kk * NDIM + n4 * 4);
    }
  }

  for (int ti = 0; ti < ntiles; ++ti) {
    const int cur_t0 = t0;
    const int nt = min(32, TDIM - cur_t0);
    // regs -> LDS
#pragma unroll
    for (int i = 0; i < 4; ++i) {
      int idx = tid + i * 256;
      int tl = idx >> 5, n4 = idx & 31;
      if (tl < nt) {
        tile[tl][n4 * 4 + 0] = pre[i].x;
        tile[tl][n4 * 4 + 1] = pre[i].y;
        tile[tl][n4 * 4 + 2] = pre[i].z;
        tile[tl][n4 * 4 + 3] = pre[i].w;
      }
    }
    __syncthreads();

    // prefetch next tile while we compute/store this one
    if (ti + 1 < ntiles) {
      int nxt = cur_t0 + 32;
      int ntn = min(32, TDIM - nxt);
#pragma unroll
      for (int i = 0; i < 4; ++i) {
        int idx = tid + i * 256;
        int tl = idx >> 5, n4 = idx & 31;
        if (tl < ntn)
          pre[i] = *reinterpret_cast<const float4*>(
              obuf + ((size_t)(bb * TDIM + nxt + tl)) * NKC + kk * NDIM + n4 * 4);
      }
    }

    if (nt == 32) {
      // full tile: thread task (n = task>>3, t4 = task&7), 4 consecutive t
#pragma unroll
      for (int pss = 0; pss < 4; ++pss) {
        int task = tid + pss * 256;
        int n = task >> 3, t4 = task & 7;
        int t = cur_t0 + t4 * 4;
        const size_t gbase = (size_t)n * TDIM + t;
        float vals[4];
#pragma unroll
        for (int j = 0; j < 4; ++j) {
          float gv, bv2;
          __builtin_memcpy(&gv, &gamma[gbase + j], 4);
          __builtin_memcpy(&bv2, &beta[gbase + j], 4);
          vals[j] = (tile[t4 * 4 + j][n] - mu) * rstd * gv + bv2;
        }
        float* dst = out + (((size_t)bb * NDIM + n) * NHEAD + kk) * TDIM + t;
        __builtin_memcpy(dst, vals, 16);
      }
    } else {
      // ragged tail (nt=5)
      for (int c2 = tid; c2 < NDIM * 32; c2 += 256) {
        int n = c2 >> 5, tl = c2 & 31;
        int t = cur_t0 + tl;
        if (t < TDIM) {
          float gmv = gamma[(size_t)n * TDIM + t];
          float btv = beta[(size_t)n * TDIM + t];
          out[(((size_t)bb * NDIM + n) * NHEAD + kk) * TDIM + t] =
              (tile[tl][n] - mu) * rstd * gmv + btv;
        }
      }
    }
    __syncthreads();
    t0 += 32;
  }
  (void)ltl; (void)ln0;
}

// ---------------------------------------------------------------------------
extern "C" void kernel_launch(void* const* d_in, const int* in_sizes, int n_in,
                              void* d_out, int out_size, void* d_ws, size_t ws_size,
                              hipStream_t stream) {
  const float* x     = (const float*)d_in[0];
  const float* Wq    = (const float*)d_in[1];
  const float* bq    = (const float*)d_in[2];
  const float* Wk    = (const float*)d_in[3];
  const float* bk    = (const float*)d_in[4];
  const float* Wv    = (const float*)d_in[5];
  const float* bv    = (const float*)d_in[6];
  const float* gamma = (const float*)d_in[7];
  const float* beta  = (const float*)d_in[8];
  float* out = (float*)d_out;

  char* wsb = (char*)d_ws;
  float* stats = (float*)wsb;                       // 1024 floats
  ushort* A = (ushort*)(wsb + 4096);                // [8320][128] bf16
  ushort* B = A + (size_t)MPAD * KPAD;              // [9216][128] bf16
  ushort* qb = B + (size_t)NCOLS * KPAD;            // [8272][3072] bf16 each
  ushort* kb = qb + (size_t)MROWS * NKC;
  ushort* vb = kb + (size_t)MROWS * NKC;
  float* obuf = (float*)(vb + (size_t)MROWS * NKC); // [8272][3072] f32
  float* part = obuf + (size_t)MROWS * NKC;         // [8272][48] f32

  convert_x_kernel<<<dim3(9, NBB), 256, 0, stream>>>(x, A);
  convert_w_kernel<<<(NCOLS * 16 + 255) / 256, 256, 0, stream>>>(Wq, Wk, Wv, B, A);
  proj_mfma_kernel<<<dim3(MPAD / 128, NCOLS / 128), 256, 0, stream>>>(
      A, B, bq, bk, bv, qb, kb, vb);
  attn_mfma_kernel<<<MROWS / 4, 256, 0, stream>>>(qb, kb, vb, obuf, part);
  ln_part_reduce_kernel<<<NBB * NHEAD, 256, 0, stream>>>(part, stats);
  transpose_apply_kernel<<<dim3(5, NHEAD, NBB), 256, 0, stream>>>(
      obuf, stats, gamma, beta, out);
}

// Round 8
// 194.718 us; speedup vs baseline: 1.0945x; 1.0945x over previous
//
#include <hip/hip_runtime.h>
#include <hip/hip_bf16.h>
#include <cstdint>

#define TDIM 517
#define FEATD 120
#define NBB 16
#define NHEAD 24
#define NDIM 128
#define NKC 3072            // NHEAD*NDIM
#define MROWS (NBB * TDIM)  // 8272
#define MPAD 8320           // 65 * 128
#define NCOLS (3 * NKC)     // 9216
#define KPAD 128
#define LN_EPS 1e-5f

typedef short bf16x8 __attribute__((ext_vector_type(8)));
typedef short bf16x4 __attribute__((ext_vector_type(4)));
typedef float f32x4 __attribute__((ext_vector_type(4)));

static __device__ __forceinline__ float bf2f(ushort u) {
  union { uint i; float f; } v; v.i = ((uint)u) << 16; return v.f;
}
static __device__ __forceinline__ ushort f2bf(float f) {
  __hip_bfloat16 h = __float2bfloat16(f);   // RNE
  return *reinterpret_cast<ushort*>(&h);
}

// ---------------------------------------------------------------------------
// K0a: x [16][120][517] f32  ->  A [row=(bb*517+tt)][kpad=128] bf16 (f>=120 zero)
// ---------------------------------------------------------------------------
__global__ __launch_bounds__(256) void convert_x_kernel(
    const float* __restrict__ x, ushort* __restrict__ A)
{
  __shared__ float tile[FEATD][65];
  const int tid = threadIdx.x;
  const int bb = blockIdx.y;
  const int t0 = blockIdx.x * 64;
  const int nt = min(64, TDIM - t0);
  for (int idx = tid; idx < FEATD * 64; idx += 256) {
    int f = idx >> 6, tl = idx & 63;
    if (tl < nt) tile[f][tl] = x[((size_t)bb * FEATD + f) * TDIM + t0 + tl];
  }
  __syncthreads();
  for (int c = tid; c < 64 * 16; c += 256) {
    int tl = c >> 4, c8 = c & 15;
    if (tl >= nt) continue;
    ushort u[8];
    if (c8 < 15) {
#pragma unroll
      for (int j = 0; j < 8; ++j) u[j] = f2bf(tile[c8 * 8 + j][tl]);
    } else {
#pragma unroll
      for (int j = 0; j < 8; ++j) u[j] = 0;
    }
    size_t row = (size_t)bb * TDIM + t0 + tl;
    *reinterpret_cast<uint4*>(A + row * KPAD + c8 * 8) = *reinterpret_cast<const uint4*>(u);
  }
}

// ---------------------------------------------------------------------------
// K0b: W{q,k,v} [3072][120] f32 -> B [9216][128] bf16; also zero A tail rows
// ---------------------------------------------------------------------------
__global__ __launch_bounds__(256) void convert_w_kernel(
    const float* __restrict__ Wq, const float* __restrict__ Wk, const float* __restrict__ Wv,
    ushort* __restrict__ B, ushort* __restrict__ A)
{
  const int c = blockIdx.x * 256 + threadIdx.x;
  if (c < NCOLS * 16) {
    int col = c >> 4, c8 = c & 15;
    ushort u[8];
    if (c8 < 15) {
      const float* W = (col < NKC)     ? (Wq + (size_t)col * FEATD)
                     : (col < 2 * NKC) ? (Wk + (size_t)(col - NKC) * FEATD)
                                       : (Wv + (size_t)(col - 2 * NKC) * FEATD);
#pragma unroll
      for (int j = 0; j < 8; ++j) u[j] = f2bf(W[c8 * 8 + j]);
    } else {
#pragma unroll
      for (int j = 0; j < 8; ++j) u[j] = 0;
    }
    *reinterpret_cast<uint4*>(B + (size_t)col * KPAD + c8 * 8) = *reinterpret_cast<const uint4*>(u);
  }
  if (c < (MPAD - MROWS) * 16) {
    uint4 z = {0, 0, 0, 0};
    *reinterpret_cast<uint4*>(A + (size_t)(MROWS + (c >> 4)) * KPAD + (c & 15) * 8) = z;
  }
}

// ---------------------------------------------------------------------------
// K1: MFMA projection GEMM (unchanged from R2)
// ---------------------------------------------------------------------------
__global__ __launch_bounds__(256) void proj_mfma_kernel(
    const ushort* __restrict__ A, const ushort* __restrict__ B,
    const float* __restrict__ bq, const float* __restrict__ bk, const float* __restrict__ bv,
    ushort* __restrict__ qb, ushort* __restrict__ kb, ushort* __restrict__ vb)
{
  __shared__ __align__(16) ushort sA[128 * KPAD];
  __shared__ __align__(16) ushort sB[128 * KPAD];
  __shared__ float sBias[128];
  const int tid  = threadIdx.x;
  const int lane = tid & 63;
  const int wave = tid >> 6;
  const int wm0  = (wave >> 1) * 64;
  const int wn0  = (wave & 1) * 64;
  const int m0   = blockIdx.x * 128;
  const int n0   = blockIdx.y * 128;
  const int mat  = blockIdx.y / 24;
  const int nloc0 = n0 - mat * NKC;
  const float* bias = (mat == 0) ? bq : (mat == 1) ? bk : bv;
  ushort* outb      = (mat == 0) ? qb : (mat == 1) ? kb : vb;

  if (tid < 128) sBias[tid] = bias[nloc0 + tid];

#pragma unroll
  for (int i = 0; i < 8; ++i) {
    int c = tid + i * 256;
    int row = c >> 4, c8 = c & 15;
    uint4 va = *reinterpret_cast<const uint4*>(A + (size_t)(m0 + row) * KPAD + c8 * 8);
    uint4 vb4 = *reinterpret_cast<const uint4*>(B + (size_t)(n0 + row) * KPAD + c8 * 8);
    *reinterpret_cast<uint4*>(&sA[row * KPAD + ((c8 ^ (row & 7)) << 3)]) = va;
    *reinterpret_cast<uint4*>(&sB[row * KPAD + ((c8 ^ (row & 7)) << 3)]) = vb4;
  }
  __syncthreads();

  f32x4 acc[4][4];
#pragma unroll
  for (int i = 0; i < 4; ++i)
#pragma unroll
    for (int j = 0; j < 4; ++j) acc[i][j] = (f32x4){0.f, 0.f, 0.f, 0.f};

  const int rl = lane & 15;
  const int kg = lane >> 4;
#pragma unroll
  for (int s = 0; s < 4; ++s) {
    bf16x8 af[4], bfr[4];
    const int c8 = s * 4 + kg;
#pragma unroll
    for (int i = 0; i < 4; ++i) {
      int row = wm0 + i * 16 + rl;
      af[i] = *reinterpret_cast<const bf16x8*>(&sA[row * KPAD + ((c8 ^ (row & 7)) << 3)]);
      int rowb = wn0 + i * 16 + rl;
      bfr[i] = *reinterpret_cast<const bf16x8*>(&sB[rowb * KPAD + ((c8 ^ (rowb & 7)) << 3)]);
    }
#pragma unroll
    for (int i = 0; i < 4; ++i)
#pragma unroll
      for (int j = 0; j < 4; ++j)
        acc[i][j] = __builtin_amdgcn_mfma_f32_16x16x32_bf16(af[i], bfr[j], acc[i][j], 0, 0, 0);
  }

  __syncthreads();
  ushort* sC = sA;
#pragma unroll
  for (int i = 0; i < 4; ++i)
#pragma unroll
    for (int j = 0; j < 4; ++j) {
      int col = wn0 + j * 16 + rl;
      float bsv = sBias[col];
#pragma unroll
      for (int r = 0; r < 4; ++r) {
        int row = wm0 + i * 16 + kg * 4 + r;
        sC[row * 128 + col] = f2bf(acc[i][j][r] + bsv);
      }
    }
  __syncthreads();
#pragma unroll
  for (int i = 0; i < 8; ++i) {
    int c = tid + i * 256;
    int row = c >> 4, c8 = c & 15;
    int grow = m0 + row;
    if (grow < MROWS)
      *reinterpret_cast<uint4*>(outb + (size_t)grow * NKC + nloc0 + c8 * 8) =
          *reinterpret_cast<const uint4*>(&sC[row * 128 + c8 * 8]);
  }
}

// ---------------------------------------------------------------------------
// K2: MFMA attention + fused LN partial stats (unchanged from R6)
// ---------------------------------------------------------------------------
#define WAVE_LDS 5760
__global__ __launch_bounds__(256) void attn_mfma_kernel(
    const ushort* __restrict__ qb, const ushort* __restrict__ kb,
    const ushort* __restrict__ vb, float* __restrict__ obuf,
    float* __restrict__ part)
{
  __shared__ __align__(16) ushort lds[4 * WAVE_LDS];
  const int tid  = threadIdx.x;
  const int wave = tid >> 6;
  const int lane = tid & 63;
  const int c = lane & 15;
  const int g = lane >> 4;
  const int p = blockIdx.x * 4 + wave;
  ushort* vT = lds + wave * WAVE_LDS;   // [n][36]: vT[n*36+m] = V[m][n]
  ushort* wL = vT + 4608;               // [row][36]: wei
  const ushort* qp = qb + (size_t)p * NKC;
  const ushort* kp = kb + (size_t)p * NKC;
  const ushort* vp = vb + (size_t)p * NKC;

  // ---- issue V global loads early (T14: hide under QK^T+softmax) ----
  uint4 vload[6];
#pragma unroll
  for (int it = 0; it < 6; ++it) {
    int idx = it * 64 + lane;
    int m = idx >> 4, n0 = (idx & 15) * 8;
    vload[it] = *reinterpret_cast<const uint4*>(vp + m * 128 + n0);
  }

  // ---- QK^T: S[kk][m], kk rows on A(Q), m cols on B(K) ----
  f32x4 sc[2][2];
#pragma unroll
  for (int i = 0; i < 2; ++i)
#pragma unroll
    for (int j = 0; j < 2; ++j) sc[i][j] = (f32x4){0.f, 0.f, 0.f, 0.f};

#pragma unroll
  for (int s = 0; s < 4; ++s) {
    bf16x8 aq[2], bk2[2];
#pragma unroll
    for (int i = 0; i < 2; ++i)
      aq[i] = *reinterpret_cast<const bf16x8*>(qp + (i * 16 + c) * 128 + s * 32 + g * 8);
#pragma unroll
    for (int j = 0; j < 2; ++j)
      bk2[j] = *reinterpret_cast<const bf16x8*>(kp + (j * 16 + c) * 128 + s * 32 + g * 8);
#pragma unroll
    for (int i = 0; i < 2; ++i)
#pragma unroll
      for (int j = 0; j < 2; ++j)
        sc[i][j] = __builtin_amdgcn_mfma_f32_16x16x32_bf16(aq[i], bk2[j], sc[i][j], 0, 0, 0);
  }

  // ---- softmax over m per row; lane holds S[i*16+g*4+r][j*16+c] ----
#pragma unroll
  for (int i = 0; i < 2; ++i) {
#pragma unroll
    for (int r = 0; r < 4; ++r) {
      float s0 = sc[i][0][r];
      float s1 = (c < 8) ? sc[i][1][r] : -1e30f;
      float mx = fmaxf(s0, s1);
#pragma unroll
      for (int d = 1; d < 16; d <<= 1) mx = fmaxf(mx, __shfl_xor(mx, d));
      float e0 = __expf(s0 - mx);
      float e1 = (c < 8) ? __expf(s1 - mx) : 0.f;
      float sum = e0 + e1;
#pragma unroll
      for (int d = 1; d < 16; d <<= 1) sum += __shfl_xor(sum, d);
      float inv = 1.f / sum;
      int row = i * 16 + g * 4 + r;
      wL[row * 36 + c]      = f2bf(e0 * inv);
      wL[row * 36 + 16 + c] = f2bf(e1 * inv);
    }
  }

  // ---- stage V transposed: vT[n*36 + m] = V[m][n] (scalar scatter) ----
#pragma unroll
  for (int it = 0; it < 6; ++it) {
    int idx = it * 64 + lane;
    int m = idx >> 4, n0 = (idx & 15) * 8;
    uint w0 = vload[it].x, w1 = vload[it].y, w2 = vload[it].z, w3 = vload[it].w;
    vT[(n0 + 0) * 36 + m] = (ushort)(w0 & 0xffff);
    vT[(n0 + 1) * 36 + m] = (ushort)(w0 >> 16);
    vT[(n0 + 2) * 36 + m] = (ushort)(w1 & 0xffff);
    vT[(n0 + 3) * 36 + m] = (ushort)(w1 >> 16);
    vT[(n0 + 4) * 36 + m] = (ushort)(w2 & 0xffff);
    vT[(n0 + 5) * 36 + m] = (ushort)(w2 >> 16);
    vT[(n0 + 6) * 36 + m] = (ushort)(w3 & 0xffff);
    vT[(n0 + 7) * 36 + m] = (ushort)(w3 >> 16);
  }
  // zero pad m=24..31 for all n (ALL halfwords — R3 lesson)
#pragma unroll
  for (int h = 0; h < 16; ++h) {
    int idx = h * 64 + lane;        // 0..1023
    int n = idx >> 3, mm = 24 + (idx & 7);
    vT[n * 36 + mm] = 0;
  }

  // ---- PV A-frags (wei): row=i*16+c, k-chunk g*8 ----
  union FU { bf16x4 h[2]; bf16x8 v; };
  bf16x8 wa[2];
#pragma unroll
  for (int i = 0; i < 2; ++i) {
    FU u;
    u.h[0] = *reinterpret_cast<const bf16x4*>(wL + (i * 16 + c) * 36 + g * 8);
    u.h[1] = *reinterpret_cast<const bf16x4*>(wL + (i * 16 + c) * 36 + g * 8 + 4);
    wa[i] = u.v;
  }

  // ---- PV + O-write + LN partial accumulation ----
  float ls0[4] = {0.f, 0.f, 0.f, 0.f}, ls20[4] = {0.f, 0.f, 0.f, 0.f};
  float ls1[4] = {0.f, 0.f, 0.f, 0.f}, ls21[4] = {0.f, 0.f, 0.f, 0.f};
  float* op = obuf + (size_t)p * NKC;
#pragma unroll
  for (int nb = 0; nb < 8; ++nb) {
    FU u;
    const ushort* vrow = vT + (nb * 16 + c) * 36 + g * 8;
    u.h[0] = *reinterpret_cast<const bf16x4*>(vrow);
    u.h[1] = *reinterpret_cast<const bf16x4*>(vrow + 4);
    bf16x8 vf = u.v;
#pragma unroll
    for (int i = 0; i < 2; ++i) {
      f32x4 pv = (f32x4){0.f, 0.f, 0.f, 0.f};
      pv = __builtin_amdgcn_mfma_f32_16x16x32_bf16(wa[i], vf, pv, 0, 0, 0);
      if (i == 0) {
#pragma unroll
        for (int q = 0; q < 4; ++q) {
          op[(g * 4 + q) * 128 + nb * 16 + c] = pv[q];
          ls0[q] += pv[q];
          ls20[q] += pv[q] * pv[q];
        }
      } else if (g < 2) {
#pragma unroll
        for (int q = 0; q < 4; ++q) {
          op[(16 + g * 4 + q) * 128 + nb * 16 + c] = pv[q];
          ls1[q] += pv[q];
          ls21[q] += pv[q] * pv[q];
        }
      }
    }
  }

  // reduce over the 16-lane c-group (xor masks < 16 stay within group)
#pragma unroll
  for (int q = 0; q < 4; ++q) {
#pragma unroll
    for (int d = 1; d < 16; d <<= 1) {
      ls0[q]  += __shfl_xor(ls0[q], d);
      ls20[q] += __shfl_xor(ls20[q], d);
      ls1[q]  += __shfl_xor(ls1[q], d);
      ls21[q] += __shfl_xor(ls21[q], d);
    }
  }
  if (c == 0) {
    float* pr = part + (size_t)p * 48;
#pragma unroll
    for (int q = 0; q < 4; ++q) {
      int kk = g * 4 + q;
      pr[2 * kk]     = ls0[q];
      pr[2 * kk + 1] = ls20[q];
    }
    if (g < 2) {
#pragma unroll
      for (int q = 0; q < 4; ++q) {
        int kk = 16 + g * 4 + q;
        pr[2 * kk]     = ls1[q];
        pr[2 * kk + 1] = ls21[q];
      }
    }
  }
}

// ---------------------------------------------------------------------------
// K3: reduce per-(bb,t) partials -> stats (mu, rstd) per (bb,kk). ~1.6 MB read.
// ---------------------------------------------------------------------------
__global__ __launch_bounds__(256) void ln_part_reduce_kernel(
    const float* __restrict__ part, float* __restrict__ stats)
{
  const int b = blockIdx.x;  // bb*24+kk
  const int bb = b / NHEAD, kk = b % NHEAD;
  const int tid = threadIdx.x;
  float s = 0.f, s2 = 0.f;
  for (int tt = tid; tt < TDIM; tt += 256) {
    const float* pr = part + ((size_t)(bb * TDIM + tt)) * 48 + 2 * kk;
    s += pr[0];
    s2 += pr[1];
  }
  __shared__ float rs[256], rs2[256];
  rs[tid] = s; rs2[tid] = s2;
  __syncthreads();
  for (int off = 128; off > 0; off >>= 1) {
    if (tid < off) { rs[tid] += rs[tid + off]; rs2[tid] += rs2[tid + off]; }
    __syncthreads();
  }
  if (tid == 0) {
    const float inv = 1.f / (NDIM * TDIM);
    float mu = rs[0] * inv;
    float var = rs2[0] * inv - mu * mu;
    stats[b] = mu;
    stats[384 + b] = rsqrtf(var + LN_EPS);
  }
}

// ---------------------------------------------------------------------------
// K4: fused transpose + LN apply. One 64t x 128n tile per block (3456 blocks).
// float4 both global sides: obuf rows 512B contiguous; out/gamma/beta runs
// 256B contiguous per n (4B-aligned dwordx4, TDIM odd). LDS pad-129: read
// banks (4tq+j+n)%32 exact 2-way (free); write 4-way (small fixed cost).
// ---------------------------------------------------------------------------
__global__ __launch_bounds__(256) void transpose_apply_kernel(
    const float* __restrict__ obuf, const float* __restrict__ stats,
    const float* __restrict__ gamma, const float* __restrict__ beta,
    float* __restrict__ out)
{
  __shared__ float tile[64][129];
  const int tid = threadIdx.x;
  const int bb = blockIdx.z, kk = blockIdx.y;
  const int t0 = blockIdx.x * 64;
  const int nt = min(64, TDIM - t0);   // 64, or 5 for the tail chunk
  const float mu = stats[bb * NHEAD + kk];
  const float rstd = stats[384 + bb * NHEAD + kk];

  // load [nt][128] from obuf, row-coalesced float4
#pragma unroll
  for (int i = 0; i < 8; ++i) {
    int idx = tid + i * 256;          // 0..2047
    int tl = idx >> 5, n4 = (idx & 31) * 4;
    if (tl < nt) {
      float4 v = *reinterpret_cast<const float4*>(
          obuf + ((size_t)(bb * TDIM + t0 + tl)) * NKC + kk * NDIM + n4);
      tile[tl][n4 + 0] = v.x;
      tile[tl][n4 + 1] = v.y;
      tile[tl][n4 + 2] = v.z;
      tile[tl][n4 + 3] = v.w;
    }
  }
  __syncthreads();

  if (nt == 64) {
#pragma unroll
    for (int ps = 0; ps < 8; ++ps) {
      int task = tid + ps * 256;      // 0..2047: n = task>>4, tq = task&15
      int n = task >> 4, tq = task & 15;
      int t = t0 + tq * 4;
      const size_t gb = (size_t)n * TDIM + t;
      float g4[4], b4[4], vals[4];
      __builtin_memcpy(g4, &gamma[gb], 16);
      __builtin_memcpy(b4, &beta[gb], 16);
#pragma unroll
      for (int j = 0; j < 4; ++j)
        vals[j] = (tile[tq * 4 + j][n] - mu) * rstd * g4[j] + b4[j];
      __builtin_memcpy(out + (((size_t)bb * NDIM + n) * NHEAD + kk) * TDIM + t, vals, 16);
    }
  } else {
    // tail: nt = 5
    for (int c2 = tid; c2 < NDIM * 5; c2 += 256) {
      int n = c2 / 5, tl = c2 % 5;
      int t = t0 + tl;
      out[(((size_t)bb * NDIM + n) * NHEAD + kk) * TDIM + t] =
          (tile[tl][n] - mu) * rstd * gamma[(size_t)n * TDIM + t] +
          beta[(size_t)n * TDIM + t];
    }
  }
}

// ---------------------------------------------------------------------------
extern "C" void kernel_launch(void* const* d_in, const int* in_sizes, int n_in,
                              void* d_out, int out_size, void* d_ws, size_t ws_size,
                              hipStream_t stream) {
  const float* x     = (const float*)d_in[0];
  const float* Wq    = (const float*)d_in[1];
  const float* bq    = (const float*)d_in[2];
  const float* Wk    = (const float*)d_in[3];
  const float* bk    = (const float*)d_in[4];
  const float* Wv    = (const float*)d_in[5];
  const float* bv    = (const float*)d_in[6];
  const float* gamma = (const float*)d_in[7];
  const float* beta  = (const float*)d_in[8];
  float* out = (float*)d_out;

  char* wsb = (char*)d_ws;
  float* stats = (float*)wsb;                       // 1024 floats
  ushort* A = (ushort*)(wsb + 4096);                // [8320][128] bf16
  ushort* B = A + (size_t)MPAD * KPAD;              // [9216][128] bf16
  ushort* qb = B + (size_t)NCOLS * KPAD;            // [8272][3072] bf16 each
  ushort* kb = qb + (size_t)MROWS * NKC;
  ushort* vb = kb + (size_t)MROWS * NKC;
  float* obuf = (float*)(vb + (size_t)MROWS * NKC); // [8272][3072] f32
  float* part = obuf + (size_t)MROWS * NKC;         // [8272][48] f32

  convert_x_kernel<<<dim3(9, NBB), 256, 0, stream>>>(x, A);
  convert_w_kernel<<<(NCOLS * 16 + 255) / 256, 256, 0, stream>>>(Wq, Wk, Wv, B, A);
  proj_mfma_kernel<<<dim3(MPAD / 128, NCOLS / 128), 256, 0, stream>>>(
      A, B, bq, bk, bv, qb, kb, vb);
  attn_mfma_kernel<<<MROWS / 4, 256, 0, stream>>>(qb, kb, vb, obuf, part);
  ln_part_reduce_kernel<<<NBB * NHEAD, 256, 0, stream>>>(part, stats);
  transpose_apply_kernel<<<dim3((TDIM + 63) / 64, NHEAD, NBB), 256, 0, stream>>>(
      obuf, stats, gamma, beta, out);
}

// Round 9
// 185.030 us; speedup vs baseline: 1.1518x; 1.0524x over previous
//
#include <hip/hip_runtime.h>
#include <hip/hip_bf16.h>
#include <cstdint>

#define TDIM 517
#define FEATD 120
#define NBB 16
#define NHEAD 24
#define NDIM 128
#define NKC 3072            // NHEAD*NDIM
#define MROWS (NBB * TDIM)  // 8272
#define MPAD 8320           // 65 * 128
#define NCOLS (3 * NKC)     // 9216
#define KPAD 128
#define LN_EPS 1e-5f

typedef short bf16x8 __attribute__((ext_vector_type(8)));
typedef short bf16x4 __attribute__((ext_vector_type(4)));
typedef float f32x4 __attribute__((ext_vector_type(4)));

static __device__ __forceinline__ float bf2f(ushort u) {
  union { uint i; float f; } v; v.i = ((uint)u) << 16; return v.f;
}
static __device__ __forceinline__ ushort f2bf(float f) {
  __hip_bfloat16 h = __float2bfloat16(f);   // RNE
  return *reinterpret_cast<ushort*>(&h);
}

// ---------------------------------------------------------------------------
// K0a: x [16][120][517] f32  ->  A [row=(bb*517+tt)][kpad=128] bf16 (f>=120 zero)
// ---------------------------------------------------------------------------
__global__ __launch_bounds__(256) void convert_x_kernel(
    const float* __restrict__ x, ushort* __restrict__ A)
{
  __shared__ float tile[FEATD][65];
  const int tid = threadIdx.x;
  const int bb = blockIdx.y;
  const int t0 = blockIdx.x * 64;
  const int nt = min(64, TDIM - t0);
  for (int idx = tid; idx < FEATD * 64; idx += 256) {
    int f = idx >> 6, tl = idx & 63;
    if (tl < nt) tile[f][tl] = x[((size_t)bb * FEATD + f) * TDIM + t0 + tl];
  }
  __syncthreads();
  for (int c = tid; c < 64 * 16; c += 256) {
    int tl = c >> 4, c8 = c & 15;
    if (tl >= nt) continue;
    ushort u[8];
    if (c8 < 15) {
#pragma unroll
      for (int j = 0; j < 8; ++j) u[j] = f2bf(tile[c8 * 8 + j][tl]);
    } else {
#pragma unroll
      for (int j = 0; j < 8; ++j) u[j] = 0;
    }
    size_t row = (size_t)bb * TDIM + t0 + tl;
    *reinterpret_cast<uint4*>(A + row * KPAD + c8 * 8) = *reinterpret_cast<const uint4*>(u);
  }
}

// ---------------------------------------------------------------------------
// K0b: W{q,k,v} [3072][120] f32 -> B [9216][128] bf16; also zero A tail rows
// ---------------------------------------------------------------------------
__global__ __launch_bounds__(256) void convert_w_kernel(
    const float* __restrict__ Wq, const float* __restrict__ Wk, const float* __restrict__ Wv,
    ushort* __restrict__ B, ushort* __restrict__ A)
{
  const int c = blockIdx.x * 256 + threadIdx.x;
  if (c < NCOLS * 16) {
    int col = c >> 4, c8 = c & 15;
    ushort u[8];
    if (c8 < 15) {
      const float* W = (col < NKC)     ? (Wq + (size_t)col * FEATD)
                     : (col < 2 * NKC) ? (Wk + (size_t)(col - NKC) * FEATD)
                                       : (Wv + (size_t)(col - 2 * NKC) * FEATD);
#pragma unroll
      for (int j = 0; j < 8; ++j) u[j] = f2bf(W[c8 * 8 + j]);
    } else {
#pragma unroll
      for (int j = 0; j < 8; ++j) u[j] = 0;
    }
    *reinterpret_cast<uint4*>(B + (size_t)col * KPAD + c8 * 8) = *reinterpret_cast<const uint4*>(u);
  }
  if (c < (MPAD - MROWS) * 16) {
    uint4 z = {0, 0, 0, 0};
    *reinterpret_cast<uint4*>(A + (size_t)(MROWS + (c >> 4)) * KPAD + (c & 15) * 8) = z;
  }
}

// ---------------------------------------------------------------------------
// K1: MFMA projection GEMM (unchanged from R2)
// ---------------------------------------------------------------------------
__global__ __launch_bounds__(256) void proj_mfma_kernel(
    const ushort* __restrict__ A, const ushort* __restrict__ B,
    const float* __restrict__ bq, const float* __restrict__ bk, const float* __restrict__ bv,
    ushort* __restrict__ qb, ushort* __restrict__ kb, ushort* __restrict__ vb)
{
  __shared__ __align__(16) ushort sA[128 * KPAD];
  __shared__ __align__(16) ushort sB[128 * KPAD];
  __shared__ float sBias[128];
  const int tid  = threadIdx.x;
  const int lane = tid & 63;
  const int wave = tid >> 6;
  const int wm0  = (wave >> 1) * 64;
  const int wn0  = (wave & 1) * 64;
  const int m0   = blockIdx.x * 128;
  const int n0   = blockIdx.y * 128;
  const int mat  = blockIdx.y / 24;
  const int nloc0 = n0 - mat * NKC;
  const float* bias = (mat == 0) ? bq : (mat == 1) ? bk : bv;
  ushort* outb      = (mat == 0) ? qb : (mat == 1) ? kb : vb;

  if (tid < 128) sBias[tid] = bias[nloc0 + tid];

#pragma unroll
  for (int i = 0; i < 8; ++i) {
    int c = tid + i * 256;
    int row = c >> 4, c8 = c & 15;
    uint4 va = *reinterpret_cast<const uint4*>(A + (size_t)(m0 + row) * KPAD + c8 * 8);
    uint4 vb4 = *reinterpret_cast<const uint4*>(B + (size_t)(n0 + row) * KPAD + c8 * 8);
    *reinterpret_cast<uint4*>(&sA[row * KPAD + ((c8 ^ (row & 7)) << 3)]) = va;
    *reinterpret_cast<uint4*>(&sB[row * KPAD + ((c8 ^ (row & 7)) << 3)]) = vb4;
  }
  __syncthreads();

  f32x4 acc[4][4];
#pragma unroll
  for (int i = 0; i < 4; ++i)
#pragma unroll
    for (int j = 0; j < 4; ++j) acc[i][j] = (f32x4){0.f, 0.f, 0.f, 0.f};

  const int rl = lane & 15;
  const int kg = lane >> 4;
#pragma unroll
  for (int s = 0; s < 4; ++s) {
    bf16x8 af[4], bfr[4];
    const int c8 = s * 4 + kg;
#pragma unroll
    for (int i = 0; i < 4; ++i) {
      int row = wm0 + i * 16 + rl;
      af[i] = *reinterpret_cast<const bf16x8*>(&sA[row * KPAD + ((c8 ^ (row & 7)) << 3)]);
      int rowb = wn0 + i * 16 + rl;
      bfr[i] = *reinterpret_cast<const bf16x8*>(&sB[rowb * KPAD + ((c8 ^ (rowb & 7)) << 3)]);
    }
#pragma unroll
    for (int i = 0; i < 4; ++i)
#pragma unroll
      for (int j = 0; j < 4; ++j)
        acc[i][j] = __builtin_amdgcn_mfma_f32_16x16x32_bf16(af[i], bfr[j], acc[i][j], 0, 0, 0);
  }

  __syncthreads();
  ushort* sC = sA;
#pragma unroll
  for (int i = 0; i < 4; ++i)
#pragma unroll
    for (int j = 0; j < 4; ++j) {
      int col = wn0 + j * 16 + rl;
      float bsv = sBias[col];
#pragma unroll
      for (int r = 0; r < 4; ++r) {
        int row = wm0 + i * 16 + kg * 4 + r;
        sC[row * 128 + col] = f2bf(acc[i][j][r] + bsv);
      }
    }
  __syncthreads();
#pragma unroll
  for (int i = 0; i < 8; ++i) {
    int c = tid + i * 256;
    int row = c >> 4, c8 = c & 15;
    int grow = m0 + row;
    if (grow < MROWS)
      *reinterpret_cast<uint4*>(outb + (size_t)grow * NKC + nloc0 + c8 * 8) =
          *reinterpret_cast<const uint4*>(&sC[row * 128 + c8 * 8]);
  }
}

// ---------------------------------------------------------------------------
// K2: MFMA attention + fused LN partial stats (unchanged from R6)
// ---------------------------------------------------------------------------
#define WAVE_LDS 5760
__global__ __launch_bounds__(256) void attn_mfma_kernel(
    const ushort* __restrict__ qb, const ushort* __restrict__ kb,
    const ushort* __restrict__ vb, float* __restrict__ obuf,
    float* __restrict__ part)
{
  __shared__ __align__(16) ushort lds[4 * WAVE_LDS];
  const int tid  = threadIdx.x;
  const int wave = tid >> 6;
  const int lane = tid & 63;
  const int c = lane & 15;
  const int g = lane >> 4;
  const int p = blockIdx.x * 4 + wave;
  ushort* vT = lds + wave * WAVE_LDS;   // [n][36]: vT[n*36+m] = V[m][n]
  ushort* wL = vT + 4608;               // [row][36]: wei
  const ushort* qp = qb + (size_t)p * NKC;
  const ushort* kp = kb + (size_t)p * NKC;
  const ushort* vp = vb + (size_t)p * NKC;

  // ---- issue V global loads early (T14: hide under QK^T+softmax) ----
  uint4 vload[6];
#pragma unroll
  for (int it = 0; it < 6; ++it) {
    int idx = it * 64 + lane;
    int m = idx >> 4, n0 = (idx & 15) * 8;
    vload[it] = *reinterpret_cast<const uint4*>(vp + m * 128 + n0);
  }

  // ---- QK^T: S[kk][m], kk rows on A(Q), m cols on B(K) ----
  f32x4 sc[2][2];
#pragma unroll
  for (int i = 0; i < 2; ++i)
#pragma unroll
    for (int j = 0; j < 2; ++j) sc[i][j] = (f32x4){0.f, 0.f, 0.f, 0.f};

#pragma unroll
  for (int s = 0; s < 4; ++s) {
    bf16x8 aq[2], bk2[2];
#pragma unroll
    for (int i = 0; i < 2; ++i)
      aq[i] = *reinterpret_cast<const bf16x8*>(qp + (i * 16 + c) * 128 + s * 32 + g * 8);
#pragma unroll
    for (int j = 0; j < 2; ++j)
      bk2[j] = *reinterpret_cast<const bf16x8*>(kp + (j * 16 + c) * 128 + s * 32 + g * 8);
#pragma unroll
    for (int i = 0; i < 2; ++i)
#pragma unroll
      for (int j = 0; j < 2; ++j)
        sc[i][j] = __builtin_amdgcn_mfma_f32_16x16x32_bf16(aq[i], bk2[j], sc[i][j], 0, 0, 0);
  }

  // ---- softmax over m per row; lane holds S[i*16+g*4+r][j*16+c] ----
#pragma unroll
  for (int i = 0; i < 2; ++i) {
#pragma unroll
    for (int r = 0; r < 4; ++r) {
      float s0 = sc[i][0][r];
      float s1 = (c < 8) ? sc[i][1][r] : -1e30f;
      float mx = fmaxf(s0, s1);
#pragma unroll
      for (int d = 1; d < 16; d <<= 1) mx = fmaxf(mx, __shfl_xor(mx, d));
      float e0 = __expf(s0 - mx);
      float e1 = (c < 8) ? __expf(s1 - mx) : 0.f;
      float sum = e0 + e1;
#pragma unroll
      for (int d = 1; d < 16; d <<= 1) sum += __shfl_xor(sum, d);
      float inv = 1.f / sum;
      int row = i * 16 + g * 4 + r;
      wL[row * 36 + c]      = f2bf(e0 * inv);
      wL[row * 36 + 16 + c] = f2bf(e1 * inv);
    }
  }

  // ---- stage V transposed: vT[n*36 + m] = V[m][n] (scalar scatter) ----
#pragma unroll
  for (int it = 0; it < 6; ++it) {
    int idx = it * 64 + lane;
    int m = idx >> 4, n0 = (idx & 15) * 8;
    uint w0 = vload[it].x, w1 = vload[it].y, w2 = vload[it].z, w3 = vload[it].w;
    vT[(n0 + 0) * 36 + m] = (ushort)(w0 & 0xffff);
    vT[(n0 + 1) * 36 + m] = (ushort)(w0 >> 16);
    vT[(n0 + 2) * 36 + m] = (ushort)(w1 & 0xffff);
    vT[(n0 + 3) * 36 + m] = (ushort)(w1 >> 16);
    vT[(n0 + 4) * 36 + m] = (ushort)(w2 & 0xffff);
    vT[(n0 + 5) * 36 + m] = (ushort)(w2 >> 16);
    vT[(n0 + 6) * 36 + m] = (ushort)(w3 & 0xffff);
    vT[(n0 + 7) * 36 + m] = (ushort)(w3 >> 16);
  }
  // zero pad m=24..31 for all n (ALL halfwords — R3 lesson)
#pragma unroll
  for (int h = 0; h < 16; ++h) {
    int idx = h * 64 + lane;        // 0..1023
    int n = idx >> 3, mm = 24 + (idx & 7);
    vT[n * 36 + mm] = 0;
  }

  // ---- PV A-frags (wei): row=i*16+c, k-chunk g*8 ----
  union FU { bf16x4 h[2]; bf16x8 v; };
  bf16x8 wa[2];
#pragma unroll
  for (int i = 0; i < 2; ++i) {
    FU u;
    u.h[0] = *reinterpret_cast<const bf16x4*>(wL + (i * 16 + c) * 36 + g * 8);
    u.h[1] = *reinterpret_cast<const bf16x4*>(wL + (i * 16 + c) * 36 + g * 8 + 4);
    wa[i] = u.v;
  }

  // ---- PV + O-write + LN partial accumulation ----
  float ls0[4] = {0.f, 0.f, 0.f, 0.f}, ls20[4] = {0.f, 0.f, 0.f, 0.f};
  float ls1[4] = {0.f, 0.f, 0.f, 0.f}, ls21[4] = {0.f, 0.f, 0.f, 0.f};
  float* op = obuf + (size_t)p * NKC;
#pragma unroll
  for (int nb = 0; nb < 8; ++nb) {
    FU u;
    const ushort* vrow = vT + (nb * 16 + c) * 36 + g * 8;
    u.h[0] = *reinterpret_cast<const bf16x4*>(vrow);
    u.h[1] = *reinterpret_cast<const bf16x4*>(vrow + 4);
    bf16x8 vf = u.v;
#pragma unroll
    for (int i = 0; i < 2; ++i) {
      f32x4 pv = (f32x4){0.f, 0.f, 0.f, 0.f};
      pv = __builtin_amdgcn_mfma_f32_16x16x32_bf16(wa[i], vf, pv, 0, 0, 0);
      if (i == 0) {
#pragma unroll
        for (int q = 0; q < 4; ++q) {
          op[(g * 4 + q) * 128 + nb * 16 + c] = pv[q];
          ls0[q] += pv[q];
          ls20[q] += pv[q] * pv[q];
        }
      } else if (g < 2) {
#pragma unroll
        for (int q = 0; q < 4; ++q) {
          op[(16 + g * 4 + q) * 128 + nb * 16 + c] = pv[q];
          ls1[q] += pv[q];
          ls21[q] += pv[q] * pv[q];
        }
      }
    }
  }

  // reduce over the 16-lane c-group (xor masks < 16 stay within group)
#pragma unroll
  for (int q = 0; q < 4; ++q) {
#pragma unroll
    for (int d = 1; d < 16; d <<= 1) {
      ls0[q]  += __shfl_xor(ls0[q], d);
      ls20[q] += __shfl_xor(ls20[q], d);
      ls1[q]  += __shfl_xor(ls1[q], d);
      ls21[q] += __shfl_xor(ls21[q], d);
    }
  }
  if (c == 0) {
    float* pr = part + (size_t)p * 48;
#pragma unroll
    for (int q = 0; q < 4; ++q) {
      int kk = g * 4 + q;
      pr[2 * kk]     = ls0[q];
      pr[2 * kk + 1] = ls20[q];
    }
    if (g < 2) {
#pragma unroll
      for (int q = 0; q < 4; ++q) {
        int kk = 16 + g * 4 + q;
        pr[2 * kk]     = ls1[q];
        pr[2 * kk + 1] = ls21[q];
      }
    }
  }
}

// ---------------------------------------------------------------------------
// K3: reduce per-(bb,t) partials -> stats (mu, rstd) per (bb,kk). ~1.6 MB read.
// ---------------------------------------------------------------------------
__global__ __launch_bounds__(256) void ln_part_reduce_kernel(
    const float* __restrict__ part, float* __restrict__ stats)
{
  const int b = blockIdx.x;  // bb*24+kk
  const int bb = b / NHEAD, kk = b % NHEAD;
  const int tid = threadIdx.x;
  float s = 0.f, s2 = 0.f;
  for (int tt = tid; tt < TDIM; tt += 256) {
    const float* pr = part + ((size_t)(bb * TDIM + tt)) * 48 + 2 * kk;
    s += pr[0];
    s2 += pr[1];
  }
  __shared__ float rs[256], rs2[256];
  rs[tid] = s; rs2[tid] = s2;
  __syncthreads();
  for (int off = 128; off > 0; off >>= 1) {
    if (tid < off) { rs[tid] += rs[tid + off]; rs2[tid] += rs2[tid + off]; }
    __syncthreads();
  }
  if (tid == 0) {
    const float inv = 1.f / (NDIM * TDIM);
    float mu = rs[0] * inv;
    float var = rs2[0] * inv - mu * mu;
    stats[b] = mu;
    stats[384 + b] = rsqrtf(var + LN_EPS);
  }
}

// ---------------------------------------------------------------------------
// K4: fused transpose + LN apply — write-page-locality version.
// Block = (bb, kk, n-group of 32, t-chunk of 256). LDS 256t x 32n f32 (32 KB)
// with per-row rotation col = (n + (t&31) + (t>>5)) & 31 -> ~2-way banks on
// BOTH phases (write lanes vary t-low/n; read lanes vary t-high/n; the
// rotation sees t's low AND high bits, unlike any pure pad).
// Store: 2 n-rows per wave x 32 lanes x float4 = 512B contiguous per instr,
// 1KB per row in 2 back-to-back instrs -> DRAM-page-friendly writes (the
// diagnosed 1.5 TB/s write wall of R5-R8's 256B scattered segments).
// ---------------------------------------------------------------------------
__global__ __launch_bounds__(256) void transpose_apply_kernel(
    const float* __restrict__ obuf, const float* __restrict__ stats,
    const float* __restrict__ gamma, const float* __restrict__ beta,
    float* __restrict__ out)
{
  __shared__ float tileF[256 * 32];
  const int tid = threadIdx.x;
  const int bb = blockIdx.z, kk = blockIdx.y;
  const int nq = blockIdx.x / 3, ch = blockIdx.x % 3;
  const int nb = nq * 32;
  const int t0 = ch * 256;
  const float mu = stats[bb * NHEAD + kk];
  const float rstd = stats[384 + bb * NHEAD + kk];

  if (ch < 2) {
    // ---- load [256t][32n] panel; scatter into rotated LDS layout ----
#pragma unroll
    for (int i = 0; i < 8; ++i) {
      int idx = tid + i * 256;           // 0..2047
      int tl = idx >> 3, nl4 = (idx & 7) * 4;
      float4 v = *reinterpret_cast<const float4*>(
          obuf + ((size_t)(bb * TDIM + t0 + tl)) * NKC + kk * NDIM + nb + nl4);
      float vv[4] = {v.x, v.y, v.z, v.w};
#pragma unroll
      for (int j = 0; j < 4; ++j) {
        int nl = nl4 + j;
        int col = (nl + (tl & 31) + (tl >> 5)) & 31;
        tileF[tl * 32 + col] = vv[j];
      }
    }
    __syncthreads();

    // ---- LN apply + store: thread (n = p*8 + tid>>5, tpos = tid&31) ----
#pragma unroll
    for (int p = 0; p < 4; ++p) {
      int nl = p * 8 + (tid >> 5);
      int n = nb + nl;
      int tpos = tid & 31;
#pragma unroll
      for (int s = 0; s < 2; ++s) {
        int tg = t0 + s * 128 + tpos * 4;
        const size_t gb = (size_t)n * TDIM + tg;
        float g4[4], b4[4], vals[4];
        __builtin_memcpy(g4, &gamma[gb], 16);
        __builtin_memcpy(b4, &beta[gb], 16);
#pragma unroll
        for (int j = 0; j < 4; ++j) {
          int tl = s * 128 + tpos * 4 + j;
          int col = (nl + (tl & 31) + (tl >> 5)) & 31;
          vals[j] = (tileF[tl * 32 + col] - mu) * rstd * g4[j] + b4[j];
        }
        __builtin_memcpy(out + (((size_t)bb * NDIM + n) * NHEAD + kk) * TDIM + tg,
                         vals, 16);
      }
    }
  } else {
    // ---- tail t = 512..516 (5 t's x 32 n), direct scalar path ----
    for (int c2 = tid; c2 < 32 * 5; c2 += 256) {
      int nl = c2 / 5, tl = c2 % 5;
      int n = nb + nl, tg = 512 + tl;
      float v = obuf[((size_t)(bb * TDIM + tg)) * NKC + kk * NDIM + n];
      out[(((size_t)bb * NDIM + n) * NHEAD + kk) * TDIM + tg] =
          (v - mu) * rstd * gamma[(size_t)n * TDIM + tg] +
          beta[(size_t)n * TDIM + tg];
    }
  }
}

// ---------------------------------------------------------------------------
extern "C" void kernel_launch(void* const* d_in, const int* in_sizes, int n_in,
                              void* d_out, int out_size, void* d_ws, size_t ws_size,
                              hipStream_t stream) {
  const float* x     = (const float*)d_in[0];
  const float* Wq    = (const float*)d_in[1];
  const float* bq    = (const float*)d_in[2];
  const float* Wk    = (const float*)d_in[3];
  const float* bk    = (const float*)d_in[4];
  const float* Wv    = (const float*)d_in[5];
  const float* bv    = (const float*)d_in[6];
  const float* gamma = (const float*)d_in[7];
  const float* beta  = (const float*)d_in[8];
  float* out = (float*)d_out;

  char* wsb = (char*)d_ws;
  float* stats = (float*)wsb;                       // 1024 floats
  ushort* A = (ushort*)(wsb + 4096);                // [8320][128] bf16
  ushort* B = A + (size_t)MPAD * KPAD;              // [9216][128] bf16
  ushort* qb = B + (size_t)NCOLS * KPAD;            // [8272][3072] bf16 each
  ushort* kb = qb + (size_t)MROWS * NKC;
  ushort* vb = kb + (size_t)MROWS * NKC;
  float* obuf = (float*)(vb + (size_t)MROWS * NKC); // [8272][3072] f32
  float* part = obuf + (size_t)MROWS * NKC;         // [8272][48] f32

  convert_x_kernel<<<dim3(9, NBB), 256, 0, stream>>>(x, A);
  convert_w_kernel<<<(NCOLS * 16 + 255) / 256, 256, 0, stream>>>(Wq, Wk, Wv, B, A);
  proj_mfma_kernel<<<dim3(MPAD / 128, NCOLS / 128), 256, 0, stream>>>(
      A, B, bq, bk, bv, qb, kb, vb);
  attn_mfma_kernel<<<MROWS / 4, 256, 0, stream>>>(qb, kb, vb, obuf, part);
  ln_part_reduce_kernel<<<NBB * NHEAD, 256, 0, stream>>>(part, stats);
  transpose_apply_kernel<<<dim3(12, NHEAD, NBB), 256, 0, stream>>>(
      obuf, stats, gamma, beta, out);
}